// Round 13
// baseline (613.247 us; speedup 1.0000x reference)
//
#include <hip/hip_runtime.h>
#include <hip/hip_bf16.h>

// Problem constants (SymNetDP): B=64, S=4096, NGB=13, NG=48, DIM=3, NCH={8,8,1}
#define BATCH 64
#define SITES 4096
#define NGB 13
#define NGRP 48
#define SDIM 3

#define LOG2E 1.44269504f
#define SPSCALE 0.014440236f   // ln2/48: converts log2-domain softplus sum

typedef __bf16 bf16x8 __attribute__((ext_vector_type(8)));
typedef float  f32x4  __attribute__((ext_vector_type(4)));

// ---------------------------------------------------------------------------
// Workspace layout:
//   Avc  : 39 f32 (pad 64)                      @ float 0
//   U    : bf16 region, 135168 elems            @ float 64
//     W0H [384][32] 12288 | W0L @12288 | W1H [384][128] @24576 (49152) |
//     W1L @73728 | W2H [48][128] @122880 (6144) | W2L @129024
//   A0   : (B,S,16) bf16 INTERLEAVED hi|lo      @ float 67648 (8 MB)
//   SW   : [3][4096] f32, ALIASES A0 (A0 dead once L1 done)
//   A1   : (B,S,16) bf16 interleaved            @ float 2164800
// Activation record: site-contiguous 32 B = h0..h7 l0..l7 (bf16).
// K-packing for NCIN=8 layers: k = j*8 + c.
//
// v23 = v22 + 1024-thread L0/L1 blocks (16 waves, NWN=2, NT_W=2) forced to
// 64 VGPR via __launch_bounds__(1024, 8).
// Rationale: L1 wall 109us vs ~35us of issue cycles -> latency-bound at
// 2 blocks/CU (only 2 independent barrier domains). Half-width waves halve
// acc (48->24) + B-frags (32->16) + staging (SPT 2->1) so the 64-VGPR
// target is near true demand (v9 precedent: NT_W=4+SPT=2 fit in 64 clean).
// 2 blocks/CU x 1024 thr = 8 waves/SIMD, 2x TLP. MT_W=3 preserved (in-wave
// group mean requires one o = 48 rows per wave). L2 (MTILES=3) stays v22.
// Tripwire: WRITE_SIZE >> 12MB = forced-bound spill -> revert.
// ---------------------------------------------------------------------------
#define OFF_AVC  0
#define OFF_U    64
#define OFF_A0   67648
#define OFF_SW   67648
#define OFF_A1   2164800
#define UW0H 0
#define UW0L 12288
#define UW1H 24576
#define UW1L 73728
#define UW2H 122880
#define UW2L 129024

// ---------------------------------------------------------------------------
// Precompute: rotated weights scaled by log2e, bf16 hi/lo split,
// [row=o*48+g][KPAD] with k=j*8+c packing for K=104 layers (k=j for L0);
// plus Avc (true units - vector channel is linear, no softplus).
// ---------------------------------------------------------------------------
__global__ __launch_bounds__(256) void precompute_kernel(
    const float* __restrict__ Psi0, const float* __restrict__ Psi1,
    const float* __restrict__ Psi2, const float* __restrict__ wtVC,
    const float* __restrict__ gdiags, const int* __restrict__ perms,
    float* __restrict__ ws)
{
    float*  Avc = ws + OFF_AVC;
    __bf16* U   = (__bf16*)(ws + OFF_U);
    int t = blockIdx.x * 256 + threadIdx.x;
    if (t < 12288) {                       // W0: [384][32], k=j
        int k = t & 31, row = t >> 5;
        int o = row / NGRP, g = row - o * NGRP;
        float w = (k < NGB) ? Psi0[o * NGB + perms[g * NGB + k]] * LOG2E : 0.f;
        __bf16 hi = (__bf16)w;
        U[UW0H + t] = hi;
        U[UW0L + t] = (__bf16)(w - (float)hi);
    } else if (t < 61440) {                // W1: [384][128], k=j*8+c
        int u = t - 12288;
        int k = u & 127, row = u >> 7;
        int o = row / NGRP, g = row - o * NGRP;
        float w = 0.f;
        if (k < 104) { int j = k >> 3, c = k & 7;
                       w = Psi1[(o * 8 + c) * NGB + perms[g * NGB + j]] * LOG2E; }
        __bf16 hi = (__bf16)w;
        U[UW1H + u] = hi;
        U[UW1L + u] = (__bf16)(w - (float)hi);
    } else if (t < 67584) {                // W2: [48][128], k=j*8+c
        int u = t - 61440;
        int k = u & 127, g = u >> 7;
        float w = 0.f;
        if (k < 104) { int j = k >> 3, c = k & 7;
                       w = Psi2[c * NGB + perms[g * NGB + j]] * LOG2E; }
        __bf16 hi = (__bf16)w;
        U[UW2H + u] = hi;
        U[UW2L + u] = (__bf16)(w - (float)hi);
    } else if (t < 67584 + 39 * NGRP) {    // Avc (true units)
        int t2 = t - 67584;
        int g = t2 % NGRP, u = t2 / NGRP;
        int d = u / NGB, n = u % NGB;
        const int row = g * SDIM + d;
        float s = 0.f;
        for (int k = 0; k < NGRP * SDIM; k++) {
            int g2 = k / SDIM, d2 = k - g2 * SDIM;
            float p = wtVC[d2 * NGB + perms[g2 * NGB + n]];
            s = fmaf(gdiags[row * (NGRP * SDIM) + k], p, s);
        }
        atomicAdd(&Avc[u], s * (1.f / 48.f));
    }
}

// ---------------------------------------------------------------------------
// build_sw: SW[d][t] = sum over edges (n,s) with NN[n,s]=t of
//   Avc[d,n] * ShellW[S2Sh[s]] * (ln2/48) / SITES.
// ---------------------------------------------------------------------------
__global__ __launch_bounds__(256) void build_sw(
    const float* __restrict__ Avc, const int* __restrict__ NN,
    const int* __restrict__ s2sh, const float* __restrict__ shellw,
    float* __restrict__ SW)
{
    int e = blockIdx.x * 256 + threadIdx.x;    // e = n*SITES + s
    if (e < NGB * SITES) {
        int n = e / SITES, s = e - n * SITES;
        float wgt = shellw[s2sh[s]] * (SPSCALE / (float)SITES);
        int t = NN[e];
        atomicAdd(&SW[t],             Avc[n] * wgt);
        atomicAdd(&SW[SITES + t],     Avc[NGB + n] * wgt);
        atomicAdd(&SW[2 * SITES + t], Avc[2 * NGB + n] * wgt);
    }
}

// ---------------------------------------------------------------------------
// MFMA gconv layer (bf16x3 split), v19 structure + KEXT diet + interleaved
// hi/lo activations + MINW occupancy control.
// Persistent-lite: per iteration compute chunk c from buffer c&1, epilogue,
// THEN gather+ds_write chunk c+1 (indices prefetched). Product-major MFMA.
// FUSED (L2): y[3] += SW[d][site]*sraw; block reduce -> atomicAdd(out).
// ---------------------------------------------------------------------------
template<int NCIN, int NCTOT, int CT, int KPAD, int KEXT, int KSTR,
         int NWAVES, int NWN, int CHUNKS, int FUSED, int MINW>
__global__ __launch_bounds__(NWAVES * 64, MINW) void layer_mfma(
    const float*  __restrict__ prevF,  // (B,S) f32 (NCIN==1)
    const __bf16* __restrict__ prevB,  // (B,S,16) interleaved (NCIN==8)
    const __bf16* __restrict__ Wh,     // [NCTOT*48][KPAD]
    const __bf16* __restrict__ Wl,
    const float*  __restrict__ bias,   // (NCTOT,)
    const int*    __restrict__ NN,     // (13, S)
    const float*  __restrict__ SWp,    // [3][SITES] (FUSED only)
    float* __restrict__ outAcc,        // (64,3) atomic target (FUSED only)
    __bf16* __restrict__ outB)         // (B,S,16) interleaved (!FUSED)
{
    constexpr int NTHR   = NWAVES * 64;
    constexpr int M      = NCTOT * NGRP;
    constexpr int MTILES = M / 16, NTILES = CT / 16;
    constexpr int NWM    = NWAVES / NWN;
    constexpr int MT_W   = MTILES / NWM, NT_W = NTILES / NWN;
    constexpr int KT     = KPAD / 32;
    constexpr int GS     = NGB * CT;              // gathered sites per chunk
    constexpr int SPT    = (GS + NTHR - 1) / NTHR;
    constexpr int CPB    = SITES / CT;            // chunks per batch
    constexpr int BUF    = CT * KSTR;             // halfwords per LDS buffer
    constexpr int BPB    = CPB / CHUNKS;          // blocks per batch

    static_assert(MT_W * 16 == NGRP, "wave covers exactly one o");
    static_assert(NWM * MT_W == MTILES && NWN * NT_W == NTILES, "");
    static_assert((KPAD & 31) == 0 && (KSTR & 7) == 0, "");
    static_assert(KEXT <= KPAD && (KEXT & 7) == 0 && KSTR >= KEXT, "");
    static_assert(CPB % CHUNKS == 0, "block stays within one batch");

    __shared__ __bf16 xh_lds[2 * BUF];
    __shared__ __bf16 xl_lds[2 * BUF];

    const int tid  = threadIdx.x;
    const int wave = tid >> 6, lane = tid & 63;
    const int m16  = lane & 15, quad = lane >> 4;

    const int bid    = blockIdx.x;
    const int b      = bid / BPB;
    const int octet  = bid % BPB;
    const int s0base = octet * (CHUNKS * CT);

    // --- per-thread staged-site slots (static decomposition) ----------------
    int sj[SPT], scol[SPT];
    bool sv[SPT];
#pragma unroll
    for (int i = 0; i < SPT; i++) {
        int site = tid + i * NTHR;
        sv[i] = (site < GS);
        int ss = sv[i] ? site : 0;
        sj[i] = ss / CT;
        scol[i] = ss % CT;
    }

    // staging of one site: interleaved record -> two b128 LDS writes (no cvt)
    auto stage_site = [&](int i, int nn, __bf16* dh, __bf16* dl) {
        if constexpr (NCIN == 1) {
            float v = prevF[(size_t)b * SITES + nn];
            __bf16 hi = (__bf16)v;
            dh[scol[i] * KSTR + sj[i]] = hi;
            dl[scol[i] * KSTR + sj[i]] = (__bf16)(v - (float)hi);
        } else {
            const bf16x8* p = (const bf16x8*)(prevB + ((size_t)(b * SITES + nn)) * 16);
            bf16x8 hv = p[0], lv = p[1];
            *(bf16x8*)(dh + scol[i] * KSTR + sj[i] * 8) = hv;
            *(bf16x8*)(dl + scol[i] * KSTR + sj[i] * 8) = lv;
        }
    };

    // --- zero K-pad (NCIN==1 only; NCIN==8 has no pad region: KEXT=104) -----
    if constexpr (NCIN == 1) {
        for (int e = tid; e < 2 * CT * (KPAD - NGB); e += NTHR) {
            int buf = e / (CT * (KPAD - NGB));
            int r   = e % (CT * (KPAD - NGB));
            int col = r / (KPAD - NGB), p = r % (KPAD - NGB);
            xh_lds[buf * BUF + col * KSTR + NGB + p] = (__bf16)0.f;
            xl_lds[buf * BUF + col * KSTR + NGB + p] = (__bf16)0.f;
        }
    }

    // --- prologue: stage chunk 0 into buffer 0; prefetch NN for chunk 1 -----
    int nnA[SPT];
#pragma unroll
    for (int i = 0; i < SPT; i++) if (sv[i]) {
        int nn = NN[sj[i] * SITES + s0base + scol[i]];
        stage_site(i, nn, xh_lds, xl_lds);
    }
    if (CHUNKS > 1) {
        const int s1 = s0base + CT;
#pragma unroll
        for (int i = 0; i < SPT; i++)
            nnA[i] = sv[i] ? NN[sj[i] * SITES + s1 + scol[i]] : 0;
    }
    __syncthreads();

    const int wave_mt0 = (wave / NWN) * MT_W;
    const int wave_nt0 = (wave % NWN) * NT_W;
    const int o_g      = (wave_mt0 * 16) / NGRP;
    const float bo     = bias[o_g] * LOG2E;

    float y0 = 0.f, y1 = 0.f, y2 = 0.f;   // FUSED accumulators

#pragma unroll 1
    for (int c = 0; c < CHUNKS; c++) {
        const int cur = c & 1;
        const __bf16* xh = xh_lds + cur * BUF;
        const __bf16* xl = xl_lds + cur * BUF;

        // --- (1) compute chunk c from buffer cur (bias in acc init) ---------
        f32x4 acc[MT_W][NT_W];
        const f32x4 binit = {bo, bo, bo, bo};
#pragma unroll
        for (int mt = 0; mt < MT_W; mt++)
#pragma unroll
            for (int nt = 0; nt < NT_W; nt++) acc[mt][nt] = binit;

#pragma unroll
        for (int kt = 0; kt < KT; kt++) {
            const int koff = kt * 32 + quad * 8;
            // B-frag clamp: for koff >= KEXT the A-weights are zero, so read
            // quad-0's (in-bounds) data instead - contributes exactly 0.
            const int koffb = (KEXT < KPAD && koff > KEXT - 8) ? (KEXT - 8) : koff;
            bf16x8 ah[MT_W], al[MT_W], bh[NT_W], bl[NT_W];
#pragma unroll
            for (int mt = 0; mt < MT_W; mt++) {
                int row = (wave_mt0 + mt) * 16 + m16;
                ah[mt] = *(const bf16x8*)(Wh + (size_t)row * KPAD + koff);
                al[mt] = *(const bf16x8*)(Wl + (size_t)row * KPAD + koff);
            }
#pragma unroll
            for (int nt = 0; nt < NT_W; nt++) {
                int cbase = ((wave_nt0 + nt) * 16 + m16) * KSTR + koffb;
                bh[nt] = *(const bf16x8*)(xh + cbase);
                bl[nt] = *(const bf16x8*)(xl + cbase);
            }
            // product-major: independent MFMAs between same-acc reuse
#pragma unroll
            for (int mt = 0; mt < MT_W; mt++)
#pragma unroll
                for (int nt = 0; nt < NT_W; nt++)
                    acc[mt][nt] = __builtin_amdgcn_mfma_f32_16x16x32_bf16(
                        ah[mt], bh[nt], acc[mt][nt], 0, 0, 0);
#pragma unroll
            for (int mt = 0; mt < MT_W; mt++)
#pragma unroll
                for (int nt = 0; nt < NT_W; nt++)
                    acc[mt][nt] = __builtin_amdgcn_mfma_f32_16x16x32_bf16(
                        al[mt], bh[nt], acc[mt][nt], 0, 0, 0);
#pragma unroll
            for (int mt = 0; mt < MT_W; mt++)
#pragma unroll
                for (int nt = 0; nt < NT_W; nt++)
                    acc[mt][nt] = __builtin_amdgcn_mfma_f32_16x16x32_bf16(
                        ah[mt], bl[nt], acc[mt][nt], 0, 0, 0);
        }

        // --- (2) epilogue: log2-domain softplus + group mean ----------------
        const int s0c = s0base + c * CT;
#pragma unroll
        for (int nt = 0; nt < NT_W; nt++) {
            float s = 0.f;
#pragma unroll
            for (int mt = 0; mt < MT_W; mt++)
#pragma unroll
                for (int r = 0; r < 4; r++) {
                    float h = acc[mt][nt][r];
                    s += fmaxf(h, 0.f) + __log2f(1.f + exp2f(-fabsf(h)));
                }
            s += __shfl_xor(s, 16);
            s += __shfl_xor(s, 32);
            if (quad == 0) {
                int site = s0c + (wave_nt0 + nt) * 16 + m16;
                if constexpr (FUSED) {
                    y0 = fmaf(SWp[site],             s, y0);
                    y1 = fmaf(SWp[SITES + site],     s, y1);
                    y2 = fmaf(SWp[2 * SITES + site], s, y2);
                } else {
                    float sv2 = s * SPSCALE;
                    __bf16 hi = (__bf16)sv2;
                    size_t idx = ((size_t)(b * SITES + site)) * 16;
                    outB[idx + o_g]     = hi;
                    outB[idx + 8 + o_g] = (__bf16)(sv2 - (float)hi);
                }
            }
        }

        // --- (3) stage chunk c+1 into buffer cur^1 (late, v13 ordering) -----
        if (c + 1 < CHUNKS) {
            __bf16* dh = xh_lds + (cur ^ 1) * BUF;
            __bf16* dl = xl_lds + (cur ^ 1) * BUF;
#pragma unroll
            for (int i = 0; i < SPT; i++) if (sv[i])
                stage_site(i, nnA[i], dh, dl);
            if (c + 2 < CHUNKS) {
                const int s2 = s0base + (c + 2) * CT;
#pragma unroll
                for (int i = 0; i < SPT; i++)
                    nnA[i] = sv[i] ? NN[sj[i] * SITES + s2 + scol[i]] : 0;
            }
        }
        __syncthreads();
    }

    // --- FUSED: block-reduce y[3] -> atomicAdd into out ---------------------
    if constexpr (FUSED) {
        float* red = (float*)xh_lds;   // last loop iter ended with a barrier
        red[tid] = y0;
        red[NTHR + tid] = y1;
        red[2 * NTHR + tid] = y2;
        __syncthreads();
        for (int st = NTHR / 2; st > 0; st >>= 1) {
            if (tid < st) {
                red[tid] += red[tid + st];
                red[NTHR + tid] += red[NTHR + tid + st];
                red[2 * NTHR + tid] += red[2 * NTHR + tid + st];
            }
            __syncthreads();
        }
        if (tid < 3) atomicAdd(&outAcc[b * 3 + tid], red[tid * NTHR]);
    }
}

// ---------------------------------------------------------------------------
extern "C" void kernel_launch(void* const* d_in, const int* in_sizes, int n_in,
                              void* d_out, int out_size, void* d_ws, size_t ws_size,
                              hipStream_t stream)
{
    const float* InStates = (const float*)d_in[0];
    const float* Psi0     = (const float*)d_in[1];
    const float* bias0    = (const float*)d_in[2];
    const float* Psi1     = (const float*)d_in[3];
    const float* bias1    = (const float*)d_in[4];
    const float* Psi2     = (const float*)d_in[5];
    const float* bias2    = (const float*)d_in[6];
    const float* wtVC     = (const float*)d_in[7];
    const float* ShellW   = (const float*)d_in[8];
    const float* gdiags   = (const float*)d_in[9];
    const int*   GnnPerms = (const int*)d_in[10];
    const int*   NNSites  = (const int*)d_in[11];
    const int*   S2Sh     = (const int*)d_in[12];

    float*  ws   = (float*)d_ws;
    float*  Avc  = ws + OFF_AVC;
    __bf16* U    = (__bf16*)(ws + OFF_U);
    __bf16* A0   = (__bf16*)(ws + OFF_A0);   // (B,S,16) interleaved
    float*  SW   = ws + OFF_SW;              // [3][4096], aliases A0
    __bf16* A1   = (__bf16*)(ws + OFF_A1);   // (B,S,16) interleaved

    float* out = (float*)d_out;      // (64,3) f32

    hipMemsetAsync(Avc, 0, 64 * sizeof(float), stream);
    hipMemsetAsync(out, 0, BATCH * 3 * sizeof(float), stream);
    precompute_kernel<<<272, 256, 0, stream>>>(Psi0, Psi1, Psi2, wtVC, gdiags,
                                               GnnPerms, ws);

    constexpr int CHUNKS = 8;
    constexpr int NBLK   = BATCH * (SITES / 64) / CHUNKS;   // 512 blocks

    // L0: 1024 thr (16 waves, NWN=2, NT_W=2), forced 8 waves/EU (VGPR<=64)
    layer_mfma<1, 8, 64, 32, 32, 40, 16, 2, CHUNKS, 0, 8>
        <<<NBLK, 1024, 0, stream>>>(
        InStates, nullptr, U + UW0H, U + UW0L, bias0, NNSites,
        nullptr, nullptr, A0);
    // L1: 1024 thr (16 waves, NWN=2, NT_W=2), forced 8 waves/EU (VGPR<=64)
    layer_mfma<8, 8, 64, 128, 104, 104, 16, 2, CHUNKS, 0, 8>
        <<<NBLK, 1024, 0, stream>>>(
        nullptr, A0, U + UW1H, U + UW1L, bias1, NNSites,
        nullptr, nullptr, A1);

    // SW build (stream-ordered after L1: A0 region is dead)
    hipMemsetAsync(SW, 0, 3 * SITES * sizeof(float), stream);
    build_sw<<<(NGB * SITES + 255) / 256, 256, 0, stream>>>(
        Avc, NNSites, S2Sh, ShellW, SW);

    // L2: 256 thr unified (MTILES=3 cannot split 16 ways), KEXT=104; fused
    layer_mfma<8, 1, 64, 128, 104, 104, 4, 4, CHUNKS, 1, 1>
        <<<NBLK, 256, 0, stream>>>(
        nullptr, A1, U + UW2H, U + UW2L, bias2, NNSites,
        SW, out, nullptr);
}

// Round 14
// 312.028 us; speedup vs baseline: 1.9654x; 1.9654x over previous
//
#include <hip/hip_runtime.h>
#include <hip/hip_bf16.h>

// Problem constants (SymNetDP): B=64, S=4096, NGB=13, NG=48, DIM=3, NCH={8,8,1}
#define BATCH 64
#define SITES 4096
#define NGB 13
#define NGRP 48
#define SDIM 3

#define LOG2E 1.44269504f
#define SPSCALE 0.014440236f   // ln2/48: converts log2-domain softplus sum

typedef __bf16 bf16x8 __attribute__((ext_vector_type(8)));
typedef float  f32x4  __attribute__((ext_vector_type(4)));

// ---------------------------------------------------------------------------
// Workspace layout:
//   Avc  : 39 f32 (pad 64)                      @ float 0
//   U    : bf16 region, 135168 elems            @ float 64
//     W0H [384][32] 12288 | W0L @12288 | W1H [384][128] @24576 (49152) |
//     W1L @73728 | W2H [48][128] @122880 (6144) | W2L @129024
//   A0   : (B,S,16) bf16 INTERLEAVED hi|lo      @ float 67648 (8 MB)
//   SW   : [3][4096] f32, ALIASES A0 (A0 dead once L1 done)
//   A1   : (B,S,16) bf16 interleaved            @ float 2164800
// Activation record: site-contiguous 32 B = h0..h7 l0..l7 (bf16).
// K-packing for NCIN=8 layers: k = j*8 + c.
//
// v24 = v22 (champion, 310.2us) + L0 KEXT=16 clamp.
// v23 post-mortem: __launch_bounds__(1024,8) forced VGPR to 32 -> massive
// scratch spill (WRITE 370MB, L1 369us). Occupancy track is closed: the
// only spill-free geometries keep 2 barrier domains/CU (v22), and v21
// showed 3 blocks/CU on L2 is neutral. Reverted wholesale.
// L0 clamp: k in [16,32) is pure zero-pad; quads 2-3 now broadcast-read
// quad-1's slot (A=0 annihilates), pad-fill shrinks 19->3 columns.
// Floor model: L1 109us = ~35us issue + ~70us gather/barrier latency that
// 2 barrier-domains/CU can't hide; 3 pipelining structures + 2 occupancy
// pushes all neutral-or-worse. This is the structural floor of this
// decomposition.
// ---------------------------------------------------------------------------
#define OFF_AVC  0
#define OFF_U    64
#define OFF_A0   67648
#define OFF_SW   67648
#define OFF_A1   2164800
#define UW0H 0
#define UW0L 12288
#define UW1H 24576
#define UW1L 73728
#define UW2H 122880
#define UW2L 129024

// ---------------------------------------------------------------------------
// Precompute: rotated weights scaled by log2e, bf16 hi/lo split,
// [row=o*48+g][KPAD] with k=j*8+c packing for K=104 layers (k=j for L0);
// plus Avc (true units - vector channel is linear, no softplus).
// ---------------------------------------------------------------------------
__global__ __launch_bounds__(256) void precompute_kernel(
    const float* __restrict__ Psi0, const float* __restrict__ Psi1,
    const float* __restrict__ Psi2, const float* __restrict__ wtVC,
    const float* __restrict__ gdiags, const int* __restrict__ perms,
    float* __restrict__ ws)
{
    float*  Avc = ws + OFF_AVC;
    __bf16* U   = (__bf16*)(ws + OFF_U);
    int t = blockIdx.x * 256 + threadIdx.x;
    if (t < 12288) {                       // W0: [384][32], k=j
        int k = t & 31, row = t >> 5;
        int o = row / NGRP, g = row - o * NGRP;
        float w = (k < NGB) ? Psi0[o * NGB + perms[g * NGB + k]] * LOG2E : 0.f;
        __bf16 hi = (__bf16)w;
        U[UW0H + t] = hi;
        U[UW0L + t] = (__bf16)(w - (float)hi);
    } else if (t < 61440) {                // W1: [384][128], k=j*8+c
        int u = t - 12288;
        int k = u & 127, row = u >> 7;
        int o = row / NGRP, g = row - o * NGRP;
        float w = 0.f;
        if (k < 104) { int j = k >> 3, c = k & 7;
                       w = Psi1[(o * 8 + c) * NGB + perms[g * NGB + j]] * LOG2E; }
        __bf16 hi = (__bf16)w;
        U[UW1H + u] = hi;
        U[UW1L + u] = (__bf16)(w - (float)hi);
    } else if (t < 67584) {                // W2: [48][128], k=j*8+c
        int u = t - 61440;
        int k = u & 127, g = u >> 7;
        float w = 0.f;
        if (k < 104) { int j = k >> 3, c = k & 7;
                       w = Psi2[c * NGB + perms[g * NGB + j]] * LOG2E; }
        __bf16 hi = (__bf16)w;
        U[UW2H + u] = hi;
        U[UW2L + u] = (__bf16)(w - (float)hi);
    } else if (t < 67584 + 39 * NGRP) {    // Avc (true units)
        int t2 = t - 67584;
        int g = t2 % NGRP, u = t2 / NGRP;
        int d = u / NGB, n = u % NGB;
        const int row = g * SDIM + d;
        float s = 0.f;
        for (int k = 0; k < NGRP * SDIM; k++) {
            int g2 = k / SDIM, d2 = k - g2 * SDIM;
            float p = wtVC[d2 * NGB + perms[g2 * NGB + n]];
            s = fmaf(gdiags[row * (NGRP * SDIM) + k], p, s);
        }
        atomicAdd(&Avc[u], s * (1.f / 48.f));
    }
}

// ---------------------------------------------------------------------------
// build_sw: SW[d][t] = sum over edges (n,s) with NN[n,s]=t of
//   Avc[d,n] * ShellW[S2Sh[s]] * (ln2/48) / SITES.
// ---------------------------------------------------------------------------
__global__ __launch_bounds__(256) void build_sw(
    const float* __restrict__ Avc, const int* __restrict__ NN,
    const int* __restrict__ s2sh, const float* __restrict__ shellw,
    float* __restrict__ SW)
{
    int e = blockIdx.x * 256 + threadIdx.x;    // e = n*SITES + s
    if (e < NGB * SITES) {
        int n = e / SITES, s = e - n * SITES;
        float wgt = shellw[s2sh[s]] * (SPSCALE / (float)SITES);
        int t = NN[e];
        atomicAdd(&SW[t],             Avc[n] * wgt);
        atomicAdd(&SW[SITES + t],     Avc[NGB + n] * wgt);
        atomicAdd(&SW[2 * SITES + t], Avc[2 * NGB + n] * wgt);
    }
}

// ---------------------------------------------------------------------------
// MFMA gconv layer (bf16x3 split), v19 structure + KEXT diet + interleaved
// hi/lo activations.
// Persistent-lite: per iteration compute chunk c from buffer c&1, epilogue,
// THEN gather+ds_write chunk c+1 (indices prefetched). Product-major MFMA.
// KEXT < KPAD: LDS holds k in [0,KEXT) only; B-frag offsets clamp to KEXT-8
// (weights are zero for k>=KEXT -> A=0 annihilates the clamped B; the
// clamped read is same-address across the affected quads -> broadcast).
// Epilogue: log2-domain softplus, bias in acc init.
// FUSED (L2): y[3] += SW[d][site]*sraw; block reduce -> atomicAdd(out).
// ---------------------------------------------------------------------------
template<int NCIN, int NCTOT, int CT, int KPAD, int KEXT, int KSTR,
         int NWAVES, int NWN, int CHUNKS, int FUSED>
__global__ __launch_bounds__(NWAVES * 64) void layer_mfma(
    const float*  __restrict__ prevF,  // (B,S) f32 (NCIN==1)
    const __bf16* __restrict__ prevB,  // (B,S,16) interleaved (NCIN==8)
    const __bf16* __restrict__ Wh,     // [NCTOT*48][KPAD]
    const __bf16* __restrict__ Wl,
    const float*  __restrict__ bias,   // (NCTOT,)
    const int*    __restrict__ NN,     // (13, S)
    const float*  __restrict__ SWp,    // [3][SITES] (FUSED only)
    float* __restrict__ outAcc,        // (64,3) atomic target (FUSED only)
    __bf16* __restrict__ outB)         // (B,S,16) interleaved (!FUSED)
{
    constexpr int NTHR   = NWAVES * 64;
    constexpr int M      = NCTOT * NGRP;
    constexpr int MTILES = M / 16, NTILES = CT / 16;
    constexpr int NWM    = NWAVES / NWN;
    constexpr int MT_W   = MTILES / NWM, NT_W = NTILES / NWN;
    constexpr int KT     = KPAD / 32;
    constexpr int GS     = NGB * CT;              // gathered sites per chunk
    constexpr int SPT    = (GS + NTHR - 1) / NTHR;
    constexpr int CPB    = SITES / CT;            // chunks per batch
    constexpr int BUF    = CT * KSTR;             // halfwords per LDS buffer
    constexpr int BPB    = CPB / CHUNKS;          // blocks per batch

    static_assert(MT_W * 16 == NGRP, "wave covers exactly one o");
    static_assert(NWM * MT_W == MTILES && NWN * NT_W == NTILES, "");
    static_assert((KPAD & 31) == 0 && (KSTR & 7) == 0, "");
    static_assert(KEXT <= KPAD && (KEXT & 7) == 0 && KSTR >= KEXT, "");
    static_assert(CPB % CHUNKS == 0, "block stays within one batch");

    __shared__ __bf16 xh_lds[2 * BUF];
    __shared__ __bf16 xl_lds[2 * BUF];

    const int tid  = threadIdx.x;
    const int wave = tid >> 6, lane = tid & 63;
    const int m16  = lane & 15, quad = lane >> 4;

    const int bid    = blockIdx.x;
    const int b      = bid / BPB;
    const int octet  = bid % BPB;
    const int s0base = octet * (CHUNKS * CT);

    // --- per-thread staged-site slots (static decomposition) ----------------
    int sj[SPT], scol[SPT];
    bool sv[SPT];
#pragma unroll
    for (int i = 0; i < SPT; i++) {
        int site = tid + i * NTHR;
        sv[i] = (site < GS);
        int ss = sv[i] ? site : 0;
        sj[i] = ss / CT;
        scol[i] = ss % CT;
    }

    // staging of one site: interleaved record -> two b128 LDS writes (no cvt)
    auto stage_site = [&](int i, int nn, __bf16* dh, __bf16* dl) {
        if constexpr (NCIN == 1) {
            float v = prevF[(size_t)b * SITES + nn];
            __bf16 hi = (__bf16)v;
            dh[scol[i] * KSTR + sj[i]] = hi;
            dl[scol[i] * KSTR + sj[i]] = (__bf16)(v - (float)hi);
        } else {
            const bf16x8* p = (const bf16x8*)(prevB + ((size_t)(b * SITES + nn)) * 16);
            bf16x8 hv = p[0], lv = p[1];
            *(bf16x8*)(dh + scol[i] * KSTR + sj[i] * 8) = hv;
            *(bf16x8*)(dl + scol[i] * KSTR + sj[i] * 8) = lv;
        }
    };

    // --- zero K-pad (NCIN==1 only; fill only [NGB, KEXT) - rest is clamped) -
    if constexpr (NCIN == 1) {
        for (int e = tid; e < 2 * CT * (KEXT - NGB); e += NTHR) {
            int buf = e / (CT * (KEXT - NGB));
            int r   = e % (CT * (KEXT - NGB));
            int col = r / (KEXT - NGB), p = r % (KEXT - NGB);
            xh_lds[buf * BUF + col * KSTR + NGB + p] = (__bf16)0.f;
            xl_lds[buf * BUF + col * KSTR + NGB + p] = (__bf16)0.f;
        }
    }

    // --- prologue: stage chunk 0 into buffer 0; prefetch NN for chunk 1 -----
    int nnA[SPT];
#pragma unroll
    for (int i = 0; i < SPT; i++) if (sv[i]) {
        int nn = NN[sj[i] * SITES + s0base + scol[i]];
        stage_site(i, nn, xh_lds, xl_lds);
    }
    if (CHUNKS > 1) {
        const int s1 = s0base + CT;
#pragma unroll
        for (int i = 0; i < SPT; i++)
            nnA[i] = sv[i] ? NN[sj[i] * SITES + s1 + scol[i]] : 0;
    }
    __syncthreads();

    const int wave_mt0 = (wave / NWN) * MT_W;
    const int wave_nt0 = (wave % NWN) * NT_W;
    const int o_g      = (wave_mt0 * 16) / NGRP;
    const float bo     = bias[o_g] * LOG2E;

    float y0 = 0.f, y1 = 0.f, y2 = 0.f;   // FUSED accumulators

#pragma unroll 1
    for (int c = 0; c < CHUNKS; c++) {
        const int cur = c & 1;
        const __bf16* xh = xh_lds + cur * BUF;
        const __bf16* xl = xl_lds + cur * BUF;

        // --- (1) compute chunk c from buffer cur (bias in acc init) ---------
        f32x4 acc[MT_W][NT_W];
        const f32x4 binit = {bo, bo, bo, bo};
#pragma unroll
        for (int mt = 0; mt < MT_W; mt++)
#pragma unroll
            for (int nt = 0; nt < NT_W; nt++) acc[mt][nt] = binit;

#pragma unroll
        for (int kt = 0; kt < KT; kt++) {
            const int koff = kt * 32 + quad * 8;
            // B-frag clamp: for koff >= KEXT the A-weights are zero, so read
            // the KEXT-8 slot instead (broadcast) - contributes exactly 0.
            const int koffb = (KEXT < KPAD && koff > KEXT - 8) ? (KEXT - 8) : koff;
            bf16x8 ah[MT_W], al[MT_W], bh[NT_W], bl[NT_W];
#pragma unroll
            for (int mt = 0; mt < MT_W; mt++) {
                int row = (wave_mt0 + mt) * 16 + m16;
                ah[mt] = *(const bf16x8*)(Wh + (size_t)row * KPAD + koff);
                al[mt] = *(const bf16x8*)(Wl + (size_t)row * KPAD + koff);
            }
#pragma unroll
            for (int nt = 0; nt < NT_W; nt++) {
                int cbase = ((wave_nt0 + nt) * 16 + m16) * KSTR + koffb;
                bh[nt] = *(const bf16x8*)(xh + cbase);
                bl[nt] = *(const bf16x8*)(xl + cbase);
            }
            // product-major: independent MFMAs between same-acc reuse
#pragma unroll
            for (int mt = 0; mt < MT_W; mt++)
#pragma unroll
                for (int nt = 0; nt < NT_W; nt++)
                    acc[mt][nt] = __builtin_amdgcn_mfma_f32_16x16x32_bf16(
                        ah[mt], bh[nt], acc[mt][nt], 0, 0, 0);
#pragma unroll
            for (int mt = 0; mt < MT_W; mt++)
#pragma unroll
                for (int nt = 0; nt < NT_W; nt++)
                    acc[mt][nt] = __builtin_amdgcn_mfma_f32_16x16x32_bf16(
                        al[mt], bh[nt], acc[mt][nt], 0, 0, 0);
#pragma unroll
            for (int mt = 0; mt < MT_W; mt++)
#pragma unroll
                for (int nt = 0; nt < NT_W; nt++)
                    acc[mt][nt] = __builtin_amdgcn_mfma_f32_16x16x32_bf16(
                        ah[mt], bl[nt], acc[mt][nt], 0, 0, 0);
        }

        // --- (2) epilogue: log2-domain softplus + group mean ----------------
        const int s0c = s0base + c * CT;
#pragma unroll
        for (int nt = 0; nt < NT_W; nt++) {
            float s = 0.f;
#pragma unroll
            for (int mt = 0; mt < MT_W; mt++)
#pragma unroll
                for (int r = 0; r < 4; r++) {
                    float h = acc[mt][nt][r];
                    s += fmaxf(h, 0.f) + __log2f(1.f + exp2f(-fabsf(h)));
                }
            s += __shfl_xor(s, 16);
            s += __shfl_xor(s, 32);
            if (quad == 0) {
                int site = s0c + (wave_nt0 + nt) * 16 + m16;
                if constexpr (FUSED) {
                    y0 = fmaf(SWp[site],             s, y0);
                    y1 = fmaf(SWp[SITES + site],     s, y1);
                    y2 = fmaf(SWp[2 * SITES + site], s, y2);
                } else {
                    float sv2 = s * SPSCALE;
                    __bf16 hi = (__bf16)sv2;
                    size_t idx = ((size_t)(b * SITES + site)) * 16;
                    outB[idx + o_g]     = hi;
                    outB[idx + 8 + o_g] = (__bf16)(sv2 - (float)hi);
                }
            }
        }

        // --- (3) stage chunk c+1 into buffer cur^1 (late, v13 ordering) -----
        if (c + 1 < CHUNKS) {
            __bf16* dh = xh_lds + (cur ^ 1) * BUF;
            __bf16* dl = xl_lds + (cur ^ 1) * BUF;
#pragma unroll
            for (int i = 0; i < SPT; i++) if (sv[i])
                stage_site(i, nnA[i], dh, dl);
            if (c + 2 < CHUNKS) {
                const int s2 = s0base + (c + 2) * CT;
#pragma unroll
                for (int i = 0; i < SPT; i++)
                    nnA[i] = sv[i] ? NN[sj[i] * SITES + s2 + scol[i]] : 0;
            }
        }
        __syncthreads();
    }

    // --- FUSED: block-reduce y[3] -> atomicAdd into out ---------------------
    if constexpr (FUSED) {
        float* red = (float*)xh_lds;   // last loop iter ended with a barrier
        red[tid] = y0;
        red[NTHR + tid] = y1;
        red[2 * NTHR + tid] = y2;
        __syncthreads();
        for (int st = NTHR / 2; st > 0; st >>= 1) {
            if (tid < st) {
                red[tid] += red[tid + st];
                red[NTHR + tid] += red[NTHR + tid + st];
                red[2 * NTHR + tid] += red[2 * NTHR + tid + st];
            }
            __syncthreads();
        }
        if (tid < 3) atomicAdd(&outAcc[b * 3 + tid], red[tid * NTHR]);
    }
}

// ---------------------------------------------------------------------------
extern "C" void kernel_launch(void* const* d_in, const int* in_sizes, int n_in,
                              void* d_out, int out_size, void* d_ws, size_t ws_size,
                              hipStream_t stream)
{
    const float* InStates = (const float*)d_in[0];
    const float* Psi0     = (const float*)d_in[1];
    const float* bias0    = (const float*)d_in[2];
    const float* Psi1     = (const float*)d_in[3];
    const float* bias1    = (const float*)d_in[4];
    const float* Psi2     = (const float*)d_in[5];
    const float* bias2    = (const float*)d_in[6];
    const float* wtVC     = (const float*)d_in[7];
    const float* ShellW   = (const float*)d_in[8];
    const float* gdiags   = (const float*)d_in[9];
    const int*   GnnPerms = (const int*)d_in[10];
    const int*   NNSites  = (const int*)d_in[11];
    const int*   S2Sh     = (const int*)d_in[12];

    float*  ws   = (float*)d_ws;
    float*  Avc  = ws + OFF_AVC;
    __bf16* U    = (__bf16*)(ws + OFF_U);
    __bf16* A0   = (__bf16*)(ws + OFF_A0);   // (B,S,16) interleaved
    float*  SW   = ws + OFF_SW;              // [3][4096], aliases A0
    __bf16* A1   = (__bf16*)(ws + OFF_A1);   // (B,S,16) interleaved

    float* out = (float*)d_out;      // (64,3) f32

    hipMemsetAsync(Avc, 0, 64 * sizeof(float), stream);
    hipMemsetAsync(out, 0, BATCH * 3 * sizeof(float), stream);
    precompute_kernel<<<272, 256, 0, stream>>>(Psi0, Psi1, Psi2, wtVC, gdiags,
                                               GnnPerms, ws);

    constexpr int CHUNKS = 8;
    constexpr int NBLK   = BATCH * (SITES / 64) / CHUNKS;   // 512 blocks

    // L0: K=13 pad 32, KEXT=16 (quads 2-3 clamped), KSTR=40; f32 in
    layer_mfma<1, 8, 64, 32, 16, 40, 8, 1, CHUNKS, 0><<<NBLK, 512, 0, stream>>>(
        InStates, nullptr, U + UW0H, U + UW0L, bias0, NNSites,
        nullptr, nullptr, A0);
    // L1: K=104 pad 128 (weights), KEXT=104 in LDS, KSTR=104
    layer_mfma<8, 8, 64, 128, 104, 104, 8, 1, CHUNKS, 0><<<NBLK, 512, 0, stream>>>(
        nullptr, A0, U + UW1H, U + UW1L, bias1, NNSites,
        nullptr, nullptr, A1);

    // SW build (stream-ordered after L1: A0 region is dead)
    hipMemsetAsync(SW, 0, 3 * SITES * sizeof(float), stream);
    build_sw<<<(NGB * SITES + 255) / 256, 256, 0, stream>>>(
        Avc, NNSites, S2Sh, ShellW, SW);

    // L2: 256 thr unified, KEXT=104; fused SW tail -> atomicAdd(out)
    layer_mfma<8, 1, 64, 128, 104, 104, 4, 4, CHUNKS, 1><<<NBLK, 256, 0, stream>>>(
        nullptr, A1, U + UW2H, U + UW2L, bias2, NNSites,
        SW, out, nullptr);
}